// Round 1
// baseline (380.059 us; speedup 1.0000x reference)
//
#include <hip/hip_runtime.h>
#include <math.h>

#define NG 1000

// ---- degree via atomic count over dst ----
__global__ void deg_kernel(const int* __restrict__ dst, float* __restrict__ deg, int E) {
    int i = blockIdx.x * blockDim.x + threadIdx.x;
    if (i < E) atomicAdd(&deg[dst[i]], 1.0f);
}

// ---- deg -> dinv (self-loop adds +1, so deg+1 >= 1 always) ----
__global__ void dinv_kernel(float* __restrict__ deg, int N) {
    int i = blockIdx.x * blockDim.x + threadIdx.x;
    if (i < N) deg[i] = rsqrtf(deg[i] + 1.0f);
}

// ---- Y[N,16] = X[N,32] @ W[16,32]^T ----
__global__ void xform32_16(const float* __restrict__ X, const float* __restrict__ W,
                           float* __restrict__ Y, int N) {
    __shared__ float sW[16 * 32];
    for (int t = threadIdx.x; t < 512; t += blockDim.x) sW[t] = W[t];
    __syncthreads();
    int i = blockIdx.x * blockDim.x + threadIdx.x;
    if (i >= N) return;
    float xv[32];
    const float4* xp = (const float4*)(X + (size_t)i * 32);
#pragma unroll
    for (int q = 0; q < 8; q++) {
        float4 v = xp[q];
        xv[4*q+0] = v.x; xv[4*q+1] = v.y; xv[4*q+2] = v.z; xv[4*q+3] = v.w;
    }
    float4* yp = (float4*)(Y + (size_t)i * 16);
#pragma unroll
    for (int j4 = 0; j4 < 4; j4++) {
        float acc[4];
#pragma unroll
        for (int jj = 0; jj < 4; jj++) {
            int j = j4 * 4 + jj;
            float a = 0.f;
#pragma unroll
            for (int k = 0; k < 32; k++) a += xv[k] * sW[j * 32 + k];
            acc[jj] = a;
        }
        float4 o; o.x = acc[0]; o.y = acc[1]; o.z = acc[2]; o.w = acc[3];
        yp[j4] = o;
    }
}

// ---- Y[N,16] = X[N,16] @ W[16,16]^T ----
__global__ void xform16_16(const float* __restrict__ X, const float* __restrict__ W,
                           float* __restrict__ Y, int N) {
    __shared__ float sW[16 * 16];
    for (int t = threadIdx.x; t < 256; t += blockDim.x) sW[t] = W[t];
    __syncthreads();
    int i = blockIdx.x * blockDim.x + threadIdx.x;
    if (i >= N) return;
    float xv[16];
    const float4* xp = (const float4*)(X + (size_t)i * 16);
#pragma unroll
    for (int q = 0; q < 4; q++) {
        float4 v = xp[q];
        xv[4*q+0] = v.x; xv[4*q+1] = v.y; xv[4*q+2] = v.z; xv[4*q+3] = v.w;
    }
    float4* yp = (float4*)(Y + (size_t)i * 16);
#pragma unroll
    for (int j4 = 0; j4 < 4; j4++) {
        float acc[4];
#pragma unroll
        for (int jj = 0; jj < 4; jj++) {
            int j = j4 * 4 + jj;
            float a = 0.f;
#pragma unroll
            for (int k = 0; k < 16; k++) a += xv[k] * sW[j * 16 + k];
            acc[jj] = a;
        }
        float4 o; o.x = acc[0]; o.y = acc[1]; o.z = acc[2]; o.w = acc[3];
        yp[j4] = o;
    }
}

// ---- edge scatter: out[dst,c] += H[src,c] * dinv[src]*dinv[dst] ----
__global__ void agg_kernel(const int* __restrict__ src, const int* __restrict__ dst,
                           const float* __restrict__ dinv, const float* __restrict__ H,
                           float* __restrict__ out, int E16) {
    int idx = blockIdx.x * blockDim.x + threadIdx.x;
    if (idx >= E16) return;
    int e = idx >> 4, c = idx & 15;
    int s = src[e], d = dst[e];
    float n = dinv[s] * dinv[d];
    atomicAdd(&out[(size_t)d * 16 + c], H[(size_t)s * 16 + c] * n);
}

// ---- epilogue conv1: B = relu(B + A*dinv^2 + b1) (self-loop + bias + relu) ----
__global__ void epi1_kernel(float* __restrict__ B, const float* __restrict__ A,
                            const float* __restrict__ dinv, const float* __restrict__ b1,
                            int N16) {
    int idx = blockIdx.x * blockDim.x + threadIdx.x;
    if (idx >= N16) return;
    int i = idx >> 4, c = idx & 15;
    float di = dinv[i];
    float v = B[idx] + A[idx] * di * di + b1[c];
    B[idx] = v > 0.f ? v : 0.f;
}

// ---- pool: pooled[batch[i],c] += (B[i,c] + A[i,c]*dinv^2); cnt[batch[i]] += 1 ----
__global__ void pool_kernel(const float* __restrict__ B, const float* __restrict__ A,
                            const float* __restrict__ dinv, const int* __restrict__ batch,
                            float* __restrict__ pooled, float* __restrict__ cnt, int N16) {
    int idx = blockIdx.x * blockDim.x + threadIdx.x;
    if (idx >= N16) return;
    int i = idx >> 4, c = idx & 15;
    int g = batch[i];
    float di = dinv[i];
    float v = B[idx] + A[idx] * di * di;
    atomicAdd(&pooled[(size_t)g * 16 + c], v);
    if (c == 0) atomicAdd(&cnt[g], 1.0f);
}

// ---- head: mean-pool finish (+b2), logits = pooled @ Wl^T + bl, softmax ----
__global__ void head_kernel(const float* __restrict__ pooled, const float* __restrict__ cnt,
                            const float* __restrict__ b2, const float* __restrict__ Wl,
                            const float* __restrict__ bl, float* __restrict__ out) {
    int g = blockIdx.x * blockDim.x + threadIdx.x;
    if (g >= NG) return;
    float c = cnt[g];
    c = c > 1.0f ? c : 1.0f;
    float inv = 1.0f / c;
    float p[16];
#pragma unroll
    for (int j = 0; j < 16; j++) p[j] = pooled[(size_t)g * 16 + j] * inv + b2[j];
    float logits[5], m = -INFINITY;
#pragma unroll
    for (int r = 0; r < 5; r++) {
        float a = bl[r];
#pragma unroll
        for (int j = 0; j < 16; j++) a += p[j] * Wl[r * 16 + j];
        logits[r] = a;
        m = fmaxf(m, a);
    }
    float s = 0.f;
#pragma unroll
    for (int r = 0; r < 5; r++) { logits[r] = expf(logits[r] - m); s += logits[r]; }
    float is = 1.0f / s;
#pragma unroll
    for (int r = 0; r < 5; r++) out[(size_t)g * 5 + r] = logits[r] * is;
}

extern "C" void kernel_launch(void* const* d_in, const int* in_sizes, int n_in,
                              void* d_out, int out_size, void* d_ws, size_t ws_size,
                              hipStream_t stream) {
    const float* x     = (const float*)d_in[0];
    const int*   edge  = (const int*)d_in[1];   // [2, E] flat: first E = src, next E = dst
    const int*   batch = (const int*)d_in[2];
    const float* W1    = (const float*)d_in[3];
    const float* b1    = (const float*)d_in[4];
    const float* W2    = (const float*)d_in[5];
    const float* b2    = (const float*)d_in[6];
    const float* Wl    = (const float*)d_in[7];
    const float* bl    = (const float*)d_in[8];

    const int N = in_sizes[0] / 32;
    const int E = in_sizes[1] / 2;
    const int* src = edge;
    const int* dst = edge + E;

    float* ws     = (float*)d_ws;
    float* dinv   = ws;                          // N   (holds deg first)
    float* B      = dinv + N;                    // N*16 (agg1 -> h1relu -> agg2)
    float* pooled = B + (size_t)N * 16;          // NG*16
    float* cnt    = pooled + (size_t)NG * 16;    // NG
    float* A      = cnt + NG;                    // N*16 (h1 -> h2)

    // zero [dinv | B | pooled | cnt] in one contiguous memset
    size_t zfloats = (size_t)N + (size_t)N * 16 + (size_t)NG * 16 + NG;
    hipMemsetAsync(ws, 0, zfloats * sizeof(float), stream);

    const int BS = 256;
    int gE   = (E + BS - 1) / BS;
    int gN   = (N + BS - 1) / BS;
    int N16  = N * 16;
    int E16  = E * 16;
    int gN16 = (N16 + BS - 1) / BS;
    int gE16 = (E16 + BS - 1) / BS;

    // degree + dinv
    deg_kernel<<<gE, BS, 0, stream>>>(dst, dinv, E);
    dinv_kernel<<<gN, BS, 0, stream>>>(dinv, N);

    // conv1: A = x @ W1^T ; B += scatter(A) ; B = relu(B + A*dinv^2 + b1)
    xform32_16<<<gN, BS, 0, stream>>>(x, W1, A, N);
    agg_kernel<<<gE16, BS, 0, stream>>>(src, dst, dinv, A, B, E16);
    epi1_kernel<<<gN16, BS, 0, stream>>>(B, A, dinv, b1, N16);

    // conv2: A = B @ W2^T ; zero B ; B += scatter(A)
    xform16_16<<<gN, BS, 0, stream>>>(B, W2, A, N);
    hipMemsetAsync(B, 0, (size_t)N16 * sizeof(float), stream);
    agg_kernel<<<gE16, BS, 0, stream>>>(src, dst, dinv, A, B, E16);

    // mean pool (b2 deferred to head) + head
    pool_kernel<<<gN16, BS, 0, stream>>>(B, A, dinv, batch, pooled, cnt, N16);
    head_kernel<<<(NG + BS - 1) / BS, BS, 0, stream>>>(pooled, cnt, b2, Wl, bl, (float*)d_out);
}